// Round 5
// baseline (3143.865 us; speedup 1.0000x reference)
//
#include <hip/hip_runtime.h>

// GraphSAGE: 3x SAGEConv(mean) + linear head.
// N=100000 nodes, E=3200000 edges, dims 64 -> 64 -> 32 -> 16 -> 1.
// Round 5: counting-sort edge partition (no global atomics at all) +
// per-bucket LDS-accumulated aggregation fused with combine.
//  - round-4 lesson: global-atomic cursor partition suffers cross-XCD
//    line sharing (7x write amp) + contention (2048 hits/counter).
//  - here every output region (pair slices, h rows) is written by exactly
//    one block -> write traffic ~= payload; all scatter atomics are LDS.
// agg-linearity: mean(h[src]) @ Wl == mean((h@Wl)[src]) -> transform first.

#define NN 100000
#define BSH 6                       // bucket = dst >> 6 (64 nodes)
#define NBK ((NN + 63) >> 6)        // 1563 buckets
#define HB 128                      // partition blocks
#define SRCMASK 0x1FFFF             // 17 bits, N=100000 < 2^17

// ---- per-block histogram of dst buckets (LDS, no global atomics) ----
__global__ void hist_k(const int* __restrict__ dst, int E, int* __restrict__ gh) {
    __shared__ int lh[NBK];
    for (int i = threadIdx.x; i < NBK; i += blockDim.x) lh[i] = 0;
    __syncthreads();
    int c = blockIdx.x;
    int chunk = (E + HB - 1) / HB;
    int b0 = c * chunk, e0 = min(b0 + chunk, E);
    for (int e = b0 + threadIdx.x; e < e0; e += blockDim.x)
        atomicAdd(&lh[dst[e] >> BSH], 1);
    __syncthreads();
    for (int i = threadIdx.x; i < NBK; i += blockDim.x) gh[i * HB + c] = lh[i];
}

// ---- one-block exclusive scan over the (bucket-major) NBK*HB table ----
__global__ void gscan_k(int* __restrict__ gh, int M, int E) {
    __shared__ int part[1024];
    int tid = threadIdx.x;
    int chunk = (M + 1023) / 1024;
    int b0 = tid * chunk, e0 = min(b0 + chunk, M);
    int s = 0;
    for (int i = b0; i < e0; ++i) s += gh[i];
    part[tid] = s;
    __syncthreads();
    for (int d = 1; d < 1024; d <<= 1) {
        int t = (tid >= d) ? part[tid - d] : 0;
        __syncthreads();
        part[tid] += t;
        __syncthreads();
    }
    int run = (tid == 0) ? 0 : part[tid - 1];
    for (int i = b0; i < e0; ++i) {
        int t = gh[i];
        gh[i] = run;
        run += t;
    }
    if (tid == 1023) gh[M] = E;   // sentinel: end of last bucket
}

// ---- place edges bucket-grouped; cursors are block-private in LDS ----
// pair[p] = src | (dst&63)<<17 ; region (bucket,block) written by ONE block.
__global__ void scatter_pack_k(const int* __restrict__ src, const int* __restrict__ dst,
                               int E, const int* __restrict__ gh,
                               unsigned* __restrict__ pair) {
    __shared__ int cur[NBK];
    int c = blockIdx.x;
    for (int i = threadIdx.x; i < NBK; i += blockDim.x) cur[i] = gh[i * HB + c];
    __syncthreads();
    int chunk = (E + HB - 1) / HB;
    int b0 = c * chunk, e0 = min(b0 + chunk, E);
    for (int e = b0 + threadIdx.x; e < e0; e += blockDim.x) {
        int dv = dst[e], sv = src[e];
        int p = atomicAdd(&cur[dv >> BSH], 1);
        pair[p] = (unsigned)sv | ((unsigned)(dv & 63) << 17);
    }
}

// ---------------- g = h @ W  (N x DIN) @ (DIN x DOUT) ----------------
template <int DIN, int DOUT>
__global__ void transform_k(const float* __restrict__ h, const float* __restrict__ W,
                            float* __restrict__ g, int N) {
    __shared__ float sW[DIN * DOUT];
    for (int i = threadIdx.x; i < DIN * DOUT; i += blockDim.x) sW[i] = W[i];
    __syncthreads();
    int idx = blockIdx.x * blockDim.x + threadIdx.x;
    if (idx >= N * DOUT) return;
    int v = idx / DOUT, j = idx % DOUT;
    const float* hv = h + (size_t)v * DIN;
    float acc = 0.f;
#pragma unroll
    for (int k = 0; k < DIN; ++k) acc = fmaf(hv[k], sW[k * DOUT + j], acc);
    g[idx] = acc;
}

// ---- per-bucket: LDS-accumulate mean-gather, fused combine ----
// out[v] = relu( (sum g[src]) * 1/deg + h[v] @ Wr + b ), v in one 64-node bucket.
template <int DIN, int DOUT>
__global__ void bucket_agg_k(const float* __restrict__ g, const unsigned* __restrict__ pair,
                             const int* __restrict__ gh, const float* __restrict__ h,
                             const float* __restrict__ Wr, const float* __restrict__ bias,
                             float* __restrict__ out, int N) {
    constexpr int Q = DOUT / 4;        // float4 chunks per row
    constexpr int EPB = 256 / Q;       // edges in flight per block pass
    constexpr int SSTR = DOUT + 1;     // odd LDS row stride -> banks spread by dl
    __shared__ float s[64 * SSTR];
    __shared__ float sW[DIN * DOUT];
    __shared__ float sh[64 * DIN];
    __shared__ float sb[DOUT];
    __shared__ int scnt[64];
    int b = blockIdx.x, tid = threadIdx.x;
    int v0 = b << BSH;
    int nv = min(64, N - v0);
    for (int i = tid; i < 64 * SSTR; i += 256) s[i] = 0.f;
    for (int i = tid; i < DIN * DOUT; i += 256) sW[i] = Wr[i];
    for (int i = tid; i < nv * DIN; i += 256) sh[i] = h[(size_t)v0 * DIN + i];
    if (tid < DOUT) sb[tid] = bias[tid];
    if (tid < 64) scnt[tid] = 0;
    __syncthreads();

    int eg = tid / Q, q = tid % Q;
    int bs = gh[b * HB], be = gh[(b + 1) * HB];
    const float4* g4 = (const float4*)g;
    int i = bs + eg;
    // 2x unroll: two independent gathers in flight per lane
    for (; i + EPB < be; i += 2 * EPB) {
        unsigned u0 = pair[i], u1 = pair[i + EPB];
        int s0 = u0 & SRCMASK, d0 = u0 >> 17;
        int s1 = u1 & SRCMASK, d1 = u1 >> 17;
        float4 a0 = g4[(size_t)s0 * Q + q];
        float4 a1 = g4[(size_t)s1 * Q + q];
        if (q == 0) { atomicAdd(&scnt[d0], 1); atomicAdd(&scnt[d1], 1); }
        int c0 = d0 * SSTR + q * 4;
        int c1 = d1 * SSTR + q * 4;
        atomicAdd(&s[c0 + 0], a0.x); atomicAdd(&s[c0 + 1], a0.y);
        atomicAdd(&s[c0 + 2], a0.z); atomicAdd(&s[c0 + 3], a0.w);
        atomicAdd(&s[c1 + 0], a1.x); atomicAdd(&s[c1 + 1], a1.y);
        atomicAdd(&s[c1 + 2], a1.z); atomicAdd(&s[c1 + 3], a1.w);
    }
    for (; i < be; i += EPB) {
        unsigned u = pair[i];
        int sv = u & SRCMASK, dl = u >> 17;
        float4 a = g4[(size_t)sv * Q + q];
        if (q == 0) atomicAdd(&scnt[dl], 1);
        int cc = dl * SSTR + q * 4;
        atomicAdd(&s[cc + 0], a.x); atomicAdd(&s[cc + 1], a.y);
        atomicAdd(&s[cc + 2], a.z); atomicAdd(&s[cc + 3], a.w);
    }
    __syncthreads();

    const float4* sW4 = (const float4*)sW;
    const float4* sb4 = (const float4*)sb;
    for (int idx = tid; idx < nv * Q; idx += 256) {
        int vl = idx / Q, jq = idx % Q;
        float4 acc = sb4[jq];
#pragma unroll
        for (int k = 0; k < DIN; ++k) {
            float hk = sh[vl * DIN + k];
            float4 w = sW4[k * Q + jq];
            acc.x = fmaf(hk, w.x, acc.x);
            acc.y = fmaf(hk, w.y, acc.y);
            acc.z = fmaf(hk, w.z, acc.z);
            acc.w = fmaf(hk, w.w, acc.w);
        }
        float iv = 1.0f / (float)max(scnt[vl], 1);
        const float* sp = s + vl * SSTR + jq * 4;
        float4 r;
        r.x = fmaxf(fmaf(sp[0], iv, acc.x), 0.f);
        r.y = fmaxf(fmaf(sp[1], iv, acc.y), 0.f);
        r.z = fmaxf(fmaf(sp[2], iv, acc.z), 0.f);
        r.w = fmaxf(fmaf(sp[3], iv, acc.w), 0.f);
        ((float4*)out)[(size_t)(v0 + vl) * Q + jq] = r;
    }
}

// ---------------- head: out = h3 @ Wc + bc (16 -> 1) ----------------
__global__ void final_k(const float* __restrict__ h, const float* __restrict__ Wc,
                        const float* __restrict__ bc, float* __restrict__ out, int N) {
    int v = blockIdx.x * blockDim.x + threadIdx.x;
    if (v >= N) return;
    float acc = bc[0];
    const float4* hv = (const float4*)(h + (size_t)v * 16);
    const float4* w = (const float4*)Wc;
#pragma unroll
    for (int q = 0; q < 4; ++q) {
        float4 a = hv[q];
        float4 b4 = w[q];
        acc += a.x * b4.x + a.y * b4.y + a.z * b4.z + a.w * b4.w;
    }
    out[v] = acc;
}

extern "C" void kernel_launch(void* const* d_in, const int* in_sizes, int n_in,
                              void* d_out, int out_size, void* d_ws, size_t ws_size,
                              hipStream_t stream) {
    const float* x   = (const float*)d_in[0];
    const int*   ei  = (const int*)d_in[1];
    const float* Wl0 = (const float*)d_in[2];
    const float* Wr0 = (const float*)d_in[3];
    const float* b0  = (const float*)d_in[4];
    const float* Wl1 = (const float*)d_in[5];
    const float* Wr1 = (const float*)d_in[6];
    const float* b1  = (const float*)d_in[7];
    const float* Wl2 = (const float*)d_in[8];
    const float* Wr2 = (const float*)d_in[9];
    const float* b2  = (const float*)d_in[10];
    const float* Wc  = (const float*)d_in[11];
    const float* bc  = (const float*)d_in[12];
    float* out = (float*)d_out;

    const int N = NN;
    const int E = in_sizes[1] / 2;
    const int* src = ei;
    const int* dst = ei + E;
    const int M = NBK * HB;            // 200064 scan entries

    char* ws = (char*)d_ws;
    const size_t MB = 1 << 20;
    int*      gh   = (int*)(ws + 0);           // (M+1) ints ~ 0.8 MB
    unsigned* pair = (unsigned*)(ws + 1 * MB); // 12.8 MB packed edges
    char*     G    = ws + 14 * MB;             // 26 MB region
    char*     A    = ws + 40 * MB;             // 26 MB region (ends 66 MB)

    float* g0 = (float*)G;                     // 25.6 MB
    float* h1 = (float*)A;                     // 25.6 MB
    float* g1 = (float*)G;                     // 12.8 MB (g0 dead)
    float* h2 = (float*)(G + 13 * MB);         // 12.8 MB
    float* g2 = (float*)A;                     // 6.4 MB (h1 dead)
    float* h3 = (float*)(A + 7 * MB);          // 6.4 MB

    // ---- counting-sort edge partition (no global atomics) ----
    hist_k<<<HB, 256, 0, stream>>>(dst, E, gh);
    gscan_k<<<1, 1024, 0, stream>>>(gh, M, E);
    scatter_pack_k<<<HB, 256, 0, stream>>>(src, dst, E, gh, pair);

    // ---- layer 0: 64 -> 64 ----
    transform_k<64, 64><<<(N * 64 + 255) / 256, 256, 0, stream>>>(x, Wl0, g0, N);
    bucket_agg_k<64, 64><<<NBK, 256, 0, stream>>>(g0, pair, gh, x, Wr0, b0, h1, N);

    // ---- layer 1: 64 -> 32 ----
    transform_k<64, 32><<<(N * 32 + 255) / 256, 256, 0, stream>>>(h1, Wl1, g1, N);
    bucket_agg_k<64, 32><<<NBK, 256, 0, stream>>>(g1, pair, gh, h1, Wr1, b1, h2, N);

    // ---- layer 2: 32 -> 16 ----
    transform_k<32, 16><<<(N * 16 + 255) / 256, 256, 0, stream>>>(h2, Wl2, g2, N);
    bucket_agg_k<32, 16><<<NBK, 256, 0, stream>>>(g2, pair, gh, h2, Wr2, b2, h3, N);

    // ---- head: 16 -> 1 ----
    final_k<<<(N + 255) / 256, 256, 0, stream>>>(h3, Wc, bc, out, N);
}

// Round 6
// 975.737 us; speedup vs baseline: 3.2220x; 3.2220x over previous
//
#include <hip/hip_runtime.h>

// GraphSAGE: 3x SAGEConv(mean) + linear head.
// N=100000 nodes, E=3200000 edges, dims 64 -> 64 -> 32 -> 16 -> 1.
// Round 6 = round-3's wave-per-node PULL aggregation (proven ~250us/layer)
//         + round-5's atomic-free counting-sort CSR build (block-exclusive
//           writes, LDS cursors) + per-bucket sort to per-node CSR.
//  - round-5 lesson: LDS-accumulated scatter agg = 28% occupancy + 204M LDS
//    atomics + 1.85M bank conflicts -> 5x slower than pull. Don't scatter.
//  - round-4 lesson: global-atomic cursors -> cross-XCD line sharing, 7x
//    write amp. All build kernels here write block-exclusive regions.
// agg-linearity: mean(h[src]) @ Wl == mean((h@Wl)[src]) -> transform first.

#define NN 100000
#define BSH 6                       // bucket = dst >> 6 (64 nodes)
#define NBK ((NN + 63) >> 6)        // 1563 buckets
#define HB 128                      // partition blocks
#define SRCMASK 0x1FFFF             // 17 bits, N=100000 < 2^17

// ---- per-block histogram of dst buckets (LDS, no global atomics) ----
__global__ void hist_k(const int* __restrict__ dst, int E, int* __restrict__ gh) {
    __shared__ int lh[NBK];
    for (int i = threadIdx.x; i < NBK; i += blockDim.x) lh[i] = 0;
    __syncthreads();
    int c = blockIdx.x;
    int chunk = (E + HB - 1) / HB;
    int b0 = c * chunk, e0 = min(b0 + chunk, E);
    for (int e = b0 + threadIdx.x; e < e0; e += blockDim.x)
        atomicAdd(&lh[dst[e] >> BSH], 1);
    __syncthreads();
    for (int i = threadIdx.x; i < NBK; i += blockDim.x) gh[i * HB + c] = lh[i];
}

// ---- one-block exclusive scan over the (bucket-major) NBK*HB table ----
__global__ void gscan_k(int* __restrict__ gh, int M, int E) {
    __shared__ int part[1024];
    int tid = threadIdx.x;
    int chunk = (M + 1023) / 1024;
    int b0 = tid * chunk, e0 = min(b0 + chunk, M);
    int s = 0;
    for (int i = b0; i < e0; ++i) s += gh[i];
    part[tid] = s;
    __syncthreads();
    for (int d = 1; d < 1024; d <<= 1) {
        int t = (tid >= d) ? part[tid - d] : 0;
        __syncthreads();
        part[tid] += t;
        __syncthreads();
    }
    int run = (tid == 0) ? 0 : part[tid - 1];
    for (int i = b0; i < e0; ++i) {
        int t = gh[i];
        gh[i] = run;
        run += t;
    }
    if (tid == 1023) gh[M] = E;   // sentinel: end of last bucket
}

// ---- place edges bucket-grouped; cursors block-private in LDS ----
// pair[p] = src | (dst&63)<<17 ; region (bucket,block) written by ONE block.
__global__ void scatter_pack_k(const int* __restrict__ src, const int* __restrict__ dst,
                               int E, const int* __restrict__ gh,
                               unsigned* __restrict__ pair) {
    __shared__ int cur[NBK];
    int c = blockIdx.x;
    for (int i = threadIdx.x; i < NBK; i += blockDim.x) cur[i] = gh[i * HB + c];
    __syncthreads();
    int chunk = (E + HB - 1) / HB;
    int b0 = c * chunk, e0 = min(b0 + chunk, E);
    for (int e = b0 + threadIdx.x; e < e0; e += blockDim.x) {
        int dv = dst[e], sv = src[e];
        int p = atomicAdd(&cur[dv >> BSH], 1);
        pair[p] = (unsigned)sv | ((unsigned)(dv & 63) << 17);
    }
}

// ---- per-bucket counting sort -> per-node CSR (adj, off, inv) ----
// One block per bucket; all global writes are block-exclusive regions.
__global__ void sort_bucket_k(const unsigned* __restrict__ pair, const int* __restrict__ gh,
                              int* __restrict__ adj, int* __restrict__ off,
                              float* __restrict__ inv, int N, int E) {
    __shared__ int lcnt[64];
    __shared__ int lbase[64];
    int b = blockIdx.x, tid = threadIdx.x;
    int base = gh[b * HB], endp = gh[(b + 1) * HB];
    int v0 = b << BSH;
    int nv = min(64, N - v0);
    if (tid < 64) lcnt[tid] = 0;
    __syncthreads();
    for (int i = base + tid; i < endp; i += blockDim.x)
        atomicAdd(&lcnt[pair[i] >> 17], 1);
    __syncthreads();
    if (tid == 0) {
        int run = 0;
        for (int d = 0; d < 64; ++d) { lbase[d] = run; run += lcnt[d]; }
    }
    __syncthreads();
    if (tid < nv) {
        off[v0 + tid] = base + lbase[tid];
        inv[v0 + tid] = 1.0f / (float)max(lcnt[tid], 1);
    }
    if (b == NBK - 1 && tid == 0) off[N] = E;
    if (tid < 64) lcnt[tid] = lbase[tid];   // reuse as cursors
    __syncthreads();
    for (int i = base + tid; i < endp; i += blockDim.x) {
        unsigned u = pair[i];
        int dl = u >> 17;
        int p = base + atomicAdd(&lcnt[dl], 1);
        adj[p] = u & SRCMASK;
    }
}

// ---------------- g = h @ W  (N x DIN) @ (DIN x DOUT) ----------------
template <int DIN, int DOUT>
__global__ void transform_k(const float* __restrict__ h, const float* __restrict__ W,
                            float* __restrict__ g, int N) {
    __shared__ float sW[DIN * DOUT];
    for (int i = threadIdx.x; i < DIN * DOUT; i += blockDim.x) sW[i] = W[i];
    __syncthreads();
    int idx = blockIdx.x * blockDim.x + threadIdx.x;
    if (idx >= N * DOUT) return;
    int v = idx / DOUT, j = idx % DOUT;
    const float* hv = h + (size_t)v * DIN;
    float acc = 0.f;
#pragma unroll
    for (int k = 0; k < DIN; ++k) acc = fmaf(hv[k], sW[k * DOUT + j], acc);
    g[idx] = acc;
}

// ---------- fused: out = relu( mean-gather(g) + h @ Wr + b ) ----------
// One wave per dst node (PULL). Q = DOUT/4 lanes cover a row as float4;
// EPT = 64/Q edge groups; 4x unroll -> 4 independent gathers/lane in flight.
template <int DIN, int DOUT, int WAVES>
__global__ void agg_combine_k(const float* __restrict__ g, const int* __restrict__ off,
                              const int* __restrict__ adj, const float* __restrict__ invc,
                              const float* __restrict__ h, const float* __restrict__ Wr,
                              const float* __restrict__ b, float* __restrict__ out, int N) {
    constexpr int Q = DOUT / 4;   // float4 lanes per node row
    constexpr int EPT = 64 / Q;   // edge groups in flight per wave
    __shared__ float sW[DIN * DOUT];
    __shared__ float sb[DOUT];
    __shared__ float sh[WAVES][DIN];
    for (int i = threadIdx.x; i < DIN * DOUT; i += blockDim.x) sW[i] = Wr[i];
    if (threadIdx.x < DOUT) sb[threadIdx.x] = b[threadIdx.x];
    int wid = threadIdx.x >> 6, lane = threadIdx.x & 63;
    int v = blockIdx.x * WAVES + wid;
    if (v < N && lane < DIN) sh[wid][lane] = h[(size_t)v * DIN + lane];
    __syncthreads();
    if (v >= N) return;

    int eg = lane / Q, q = lane % Q;
    int beg = off[v], end = off[v + 1];
    const float4* g4 = (const float4*)g;
    float4 acc = make_float4(0.f, 0.f, 0.f, 0.f);

    int i = beg + eg;
    for (; i + 3 * EPT < end; i += 4 * EPT) {
        int s0 = adj[i];
        int s1 = adj[i + EPT];
        int s2 = adj[i + 2 * EPT];
        int s3 = adj[i + 3 * EPT];
        float4 a0 = g4[(size_t)s0 * Q + q];
        float4 a1 = g4[(size_t)s1 * Q + q];
        float4 a2 = g4[(size_t)s2 * Q + q];
        float4 a3 = g4[(size_t)s3 * Q + q];
        acc.x += (a0.x + a1.x) + (a2.x + a3.x);
        acc.y += (a0.y + a1.y) + (a2.y + a3.y);
        acc.z += (a0.z + a1.z) + (a2.z + a3.z);
        acc.w += (a0.w + a1.w) + (a2.w + a3.w);
    }
    for (; i < end; i += EPT) {
        int sv = adj[i];
        float4 gv = g4[(size_t)sv * Q + q];
        acc.x += gv.x; acc.y += gv.y; acc.z += gv.z; acc.w += gv.w;
    }
#pragma unroll
    for (int d = Q; d < 64; d <<= 1) {
        acc.x += __shfl_xor(acc.x, d, 64);
        acc.y += __shfl_xor(acc.y, d, 64);
        acc.z += __shfl_xor(acc.z, d, 64);
        acc.w += __shfl_xor(acc.w, d, 64);
    }
    if (eg == 0) {
        float iv = invc[v];
        float o[4];
#pragma unroll
        for (int c = 0; c < 4; ++c) {
            int j = q * 4 + c;
            float a = sb[j];
#pragma unroll
            for (int k = 0; k < DIN; ++k) a = fmaf(sh[wid][k], sW[k * DOUT + j], a);
            o[c] = a;
        }
        float4 r;
        r.x = fmaxf(acc.x * iv + o[0], 0.f);
        r.y = fmaxf(acc.y * iv + o[1], 0.f);
        r.z = fmaxf(acc.z * iv + o[2], 0.f);
        r.w = fmaxf(acc.w * iv + o[3], 0.f);
        ((float4*)out)[(size_t)v * Q + q] = r;
    }
}

// ---------------- head: out = h3 @ Wc + bc (16 -> 1) ----------------
__global__ void final_k(const float* __restrict__ h, const float* __restrict__ Wc,
                        const float* __restrict__ bc, float* __restrict__ out, int N) {
    int v = blockIdx.x * blockDim.x + threadIdx.x;
    if (v >= N) return;
    float acc = bc[0];
    const float4* hv = (const float4*)(h + (size_t)v * 16);
    const float4* w = (const float4*)Wc;
#pragma unroll
    for (int q = 0; q < 4; ++q) {
        float4 a = hv[q];
        float4 b4 = w[q];
        acc += a.x * b4.x + a.y * b4.y + a.z * b4.z + a.w * b4.w;
    }
    out[v] = acc;
}

extern "C" void kernel_launch(void* const* d_in, const int* in_sizes, int n_in,
                              void* d_out, int out_size, void* d_ws, size_t ws_size,
                              hipStream_t stream) {
    const float* x   = (const float*)d_in[0];
    const int*   ei  = (const int*)d_in[1];
    const float* Wl0 = (const float*)d_in[2];
    const float* Wr0 = (const float*)d_in[3];
    const float* b0  = (const float*)d_in[4];
    const float* Wl1 = (const float*)d_in[5];
    const float* Wr1 = (const float*)d_in[6];
    const float* b1  = (const float*)d_in[7];
    const float* Wl2 = (const float*)d_in[8];
    const float* Wr2 = (const float*)d_in[9];
    const float* b2  = (const float*)d_in[10];
    const float* Wc  = (const float*)d_in[11];
    const float* bc  = (const float*)d_in[12];
    float* out = (float*)d_out;

    const int N = NN;
    const int E = in_sizes[1] / 2;
    const int* src = ei;
    const int* dst = ei + E;
    const int M = NBK * HB;            // 200064 scan entries

    char* ws = (char*)d_ws;
    const size_t KB = 1 << 10;
    const size_t MB = 1 << 20;
    int*      gh   = (int*)(ws + 0);             // (M+1) ints ~ 0.8 MB
    int*      off  = (int*)(ws + 1 * MB);        // 400 KB
    float*    inv  = (float*)(ws + 1536 * KB);   // 400 KB
    unsigned* pair = (unsigned*)(ws + 2 * MB);   // 12.8 MB packed edges
    int*      adj  = (int*)(ws + 15 * MB);       // 12.8 MB CSR adjacency
    char*     G    = ws + 28 * MB;               // 26 MB region
    char*     A    = ws + 54 * MB;               // 26 MB region (ends 80 MB)

    float* g0 = (float*)G;                       // 25.6 MB
    float* h1 = (float*)A;                       // 25.6 MB
    float* g1 = (float*)G;                       // 12.8 MB (g0 dead)
    float* h2 = (float*)(G + 13 * MB);           // 12.8 MB
    float* g2 = (float*)A;                       // 6.4 MB (h1 dead)
    float* h3 = (float*)(A + 7 * MB);            // 6.4 MB

    // ---- counting-sort CSR build (no global atomics anywhere) ----
    hist_k<<<HB, 256, 0, stream>>>(dst, E, gh);
    gscan_k<<<1, 1024, 0, stream>>>(gh, M, E);
    scatter_pack_k<<<HB, 256, 0, stream>>>(src, dst, E, gh, pair);
    sort_bucket_k<<<NBK, 256, 0, stream>>>(pair, gh, adj, off, inv, N, E);

    // ---- layer 0: 64 -> 64 ----
    transform_k<64, 64><<<(N * 64 + 255) / 256, 256, 0, stream>>>(x, Wl0, g0, N);
    agg_combine_k<64, 64, 4><<<(N + 3) / 4, 256, 0, stream>>>(g0, off, adj, inv, x, Wr0, b0, h1, N);

    // ---- layer 1: 64 -> 32 ----
    transform_k<64, 32><<<(N * 32 + 255) / 256, 256, 0, stream>>>(h1, Wl1, g1, N);
    agg_combine_k<64, 32, 4><<<(N + 3) / 4, 256, 0, stream>>>(g1, off, adj, inv, h1, Wr1, b1, h2, N);

    // ---- layer 2: 32 -> 16 ----
    transform_k<32, 16><<<(N * 16 + 255) / 256, 256, 0, stream>>>(h2, Wl2, g2, N);
    agg_combine_k<32, 16, 4><<<(N + 3) / 4, 256, 0, stream>>>(g2, off, adj, inv, h2, Wr2, b2, h3, N);

    // ---- head: 16 -> 1 ----
    final_k<<<(N + 255) / 256, 256, 0, stream>>>(h3, Wc, bc, out, N);
}

// Round 7
// 667.515 us; speedup vs baseline: 4.7098x; 1.4617x over previous
//
#include <hip/hip_runtime.h>

// GraphSAGE: 3x SAGEConv(mean) + linear head.
// N=100000 nodes, E=3200000 edges, dims 64 -> 64 -> 32 -> 16 -> 1.
// Round 7 = round 6 with the single-block gscan_k (320us @ 0.16% occupancy,
// 33% of runtime) replaced by a 3-phase parallel scan (8192 segments).
//  - round-5 lesson: LDS-accumulated scatter agg -> don't scatter; PULL.
//  - round-4 lesson: global-atomic cursors -> cross-XCD line sharing;
//    all build kernels write block-exclusive regions, atomics only in LDS.
// agg-linearity: mean(h[src]) @ Wl == mean((h@Wl)[src]) -> transform first.

#define NN 100000
#define BSH 6                       // bucket = dst >> 6 (64 nodes)
#define NBK ((NN + 63) >> 6)        // 1563 buckets
#define HB 128                      // partition blocks
#define SRCMASK 0x1FFFF             // 17 bits, N=100000 < 2^17
#define NSEG 8192                   // scan segments
#define SCB 32                      // scan blocks (NSEG/256)

// ---- per-block histogram of dst buckets (LDS, no global atomics) ----
__global__ void hist_k(const int* __restrict__ dst, int E, int* __restrict__ gh) {
    __shared__ int lh[NBK];
    for (int i = threadIdx.x; i < NBK; i += blockDim.x) lh[i] = 0;
    __syncthreads();
    int c = blockIdx.x;
    int chunk = (E + HB - 1) / HB;
    int b0 = c * chunk, e0 = min(b0 + chunk, E);
    for (int e = b0 + threadIdx.x; e < e0; e += blockDim.x)
        atomicAdd(&lh[dst[e] >> BSH], 1);
    __syncthreads();
    for (int i = threadIdx.x; i < NBK; i += blockDim.x) gh[i * HB + c] = lh[i];
}

// ---- 3-phase parallel exclusive scan over gh[0..M) ----
__global__ void scanA_k(const int* __restrict__ gh, int M, int* __restrict__ segsum) {
    int t = blockIdx.x * blockDim.x + threadIdx.x;      // 0..NSEG
    int cht = (M + NSEG - 1) / NSEG;
    int b0 = t * cht, e0 = min(b0 + cht, M);
    int s = 0;
    for (int i = b0; i < e0; ++i) s += gh[i];
    segsum[t] = s;
}

__global__ void scanB_k(int* __restrict__ segsum, int* __restrict__ gh, int M, int E) {
    __shared__ int part[1024];
    int tid = threadIdx.x;
    constexpr int SPT = NSEG / 1024;   // 8 segments per thread
    int loc[SPT];
    int s = 0;
#pragma unroll
    for (int k = 0; k < SPT; ++k) { loc[k] = segsum[tid * SPT + k]; s += loc[k]; }
    part[tid] = s;
    __syncthreads();
    for (int d = 1; d < 1024; d <<= 1) {
        int t = (tid >= d) ? part[tid - d] : 0;
        __syncthreads();
        part[tid] += t;
        __syncthreads();
    }
    int run = (tid == 0) ? 0 : part[tid - 1];
#pragma unroll
    for (int k = 0; k < SPT; ++k) { int t = loc[k]; segsum[tid * SPT + k] = run; run += t; }
    if (tid == 0) gh[M] = E;   // sentinel: end of last bucket
}

__global__ void scanC_k(int* __restrict__ gh, int M, const int* __restrict__ segsum) {
    int t = blockIdx.x * blockDim.x + threadIdx.x;
    int cht = (M + NSEG - 1) / NSEG;
    int b0 = t * cht, e0 = min(b0 + cht, M);
    int run = segsum[t];
    for (int i = b0; i < e0; ++i) {
        int v = gh[i];
        gh[i] = run;
        run += v;
    }
}

// ---- place edges bucket-grouped; cursors block-private in LDS ----
// pair[p] = src | (dst&63)<<17 ; region (bucket,block) written by ONE block.
__global__ void scatter_pack_k(const int* __restrict__ src, const int* __restrict__ dst,
                               int E, const int* __restrict__ gh,
                               unsigned* __restrict__ pair) {
    __shared__ int cur[NBK];
    int c = blockIdx.x;
    for (int i = threadIdx.x; i < NBK; i += blockDim.x) cur[i] = gh[i * HB + c];
    __syncthreads();
    int chunk = (E + HB - 1) / HB;
    int b0 = c * chunk, e0 = min(b0 + chunk, E);
    for (int e = b0 + threadIdx.x; e < e0; e += blockDim.x) {
        int dv = dst[e], sv = src[e];
        int p = atomicAdd(&cur[dv >> BSH], 1);
        pair[p] = (unsigned)sv | ((unsigned)(dv & 63) << 17);
    }
}

// ---- per-bucket counting sort -> per-node CSR (adj, off, inv) ----
__global__ void sort_bucket_k(const unsigned* __restrict__ pair, const int* __restrict__ gh,
                              int* __restrict__ adj, int* __restrict__ off,
                              float* __restrict__ inv, int N, int E) {
    __shared__ int lcnt[64];
    __shared__ int lbase[64];
    int b = blockIdx.x, tid = threadIdx.x;
    int base = gh[b * HB], endp = gh[(b + 1) * HB];
    int v0 = b << BSH;
    int nv = min(64, N - v0);
    if (tid < 64) lcnt[tid] = 0;
    __syncthreads();
    for (int i = base + tid; i < endp; i += blockDim.x)
        atomicAdd(&lcnt[pair[i] >> 17], 1);
    __syncthreads();
    if (tid == 0) {
        int run = 0;
        for (int d = 0; d < 64; ++d) { lbase[d] = run; run += lcnt[d]; }
    }
    __syncthreads();
    if (tid < nv) {
        off[v0 + tid] = base + lbase[tid];
        inv[v0 + tid] = 1.0f / (float)max(lcnt[tid], 1);
    }
    if (b == NBK - 1 && tid == 0) off[N] = E;
    if (tid < 64) lcnt[tid] = lbase[tid];   // reuse as cursors
    __syncthreads();
    for (int i = base + tid; i < endp; i += blockDim.x) {
        unsigned u = pair[i];
        int dl = u >> 17;
        int p = base + atomicAdd(&lcnt[dl], 1);
        adj[p] = u & SRCMASK;
    }
}

// ---------------- g = h @ W  (N x DIN) @ (DIN x DOUT) ----------------
template <int DIN, int DOUT>
__global__ void transform_k(const float* __restrict__ h, const float* __restrict__ W,
                            float* __restrict__ g, int N) {
    __shared__ float sW[DIN * DOUT];
    for (int i = threadIdx.x; i < DIN * DOUT; i += blockDim.x) sW[i] = W[i];
    __syncthreads();
    int idx = blockIdx.x * blockDim.x + threadIdx.x;
    if (idx >= N * DOUT) return;
    int v = idx / DOUT, j = idx % DOUT;
    const float* hv = h + (size_t)v * DIN;
    float acc = 0.f;
#pragma unroll
    for (int k = 0; k < DIN; ++k) acc = fmaf(hv[k], sW[k * DOUT + j], acc);
    g[idx] = acc;
}

// ---------- fused: out = relu( mean-gather(g) + h @ Wr + b ) ----------
// One wave per dst node (PULL). Q = DOUT/4 lanes cover a row as float4;
// EPT = 64/Q edge groups; 4x unroll -> 4 independent gathers/lane in flight.
template <int DIN, int DOUT, int WAVES>
__global__ void agg_combine_k(const float* __restrict__ g, const int* __restrict__ off,
                              const int* __restrict__ adj, const float* __restrict__ invc,
                              const float* __restrict__ h, const float* __restrict__ Wr,
                              const float* __restrict__ b, float* __restrict__ out, int N) {
    constexpr int Q = DOUT / 4;   // float4 lanes per node row
    constexpr int EPT = 64 / Q;   // edge groups in flight per wave
    __shared__ float sW[DIN * DOUT];
    __shared__ float sb[DOUT];
    __shared__ float sh[WAVES][DIN];
    for (int i = threadIdx.x; i < DIN * DOUT; i += blockDim.x) sW[i] = Wr[i];
    if (threadIdx.x < DOUT) sb[threadIdx.x] = b[threadIdx.x];
    int wid = threadIdx.x >> 6, lane = threadIdx.x & 63;
    int v = blockIdx.x * WAVES + wid;
    if (v < N && lane < DIN) sh[wid][lane] = h[(size_t)v * DIN + lane];
    __syncthreads();
    if (v >= N) return;

    int eg = lane / Q, q = lane % Q;
    int beg = off[v], end = off[v + 1];
    const float4* g4 = (const float4*)g;
    float4 acc = make_float4(0.f, 0.f, 0.f, 0.f);

    int i = beg + eg;
    for (; i + 3 * EPT < end; i += 4 * EPT) {
        int s0 = adj[i];
        int s1 = adj[i + EPT];
        int s2 = adj[i + 2 * EPT];
        int s3 = adj[i + 3 * EPT];
        float4 a0 = g4[(size_t)s0 * Q + q];
        float4 a1 = g4[(size_t)s1 * Q + q];
        float4 a2 = g4[(size_t)s2 * Q + q];
        float4 a3 = g4[(size_t)s3 * Q + q];
        acc.x += (a0.x + a1.x) + (a2.x + a3.x);
        acc.y += (a0.y + a1.y) + (a2.y + a3.y);
        acc.z += (a0.z + a1.z) + (a2.z + a3.z);
        acc.w += (a0.w + a1.w) + (a2.w + a3.w);
    }
    for (; i < end; i += EPT) {
        int sv = adj[i];
        float4 gv = g4[(size_t)sv * Q + q];
        acc.x += gv.x; acc.y += gv.y; acc.z += gv.z; acc.w += gv.w;
    }
#pragma unroll
    for (int d = Q; d < 64; d <<= 1) {
        acc.x += __shfl_xor(acc.x, d, 64);
        acc.y += __shfl_xor(acc.y, d, 64);
        acc.z += __shfl_xor(acc.z, d, 64);
        acc.w += __shfl_xor(acc.w, d, 64);
    }
    if (eg == 0) {
        float iv = invc[v];
        float o[4];
#pragma unroll
        for (int c = 0; c < 4; ++c) {
            int j = q * 4 + c;
            float a = sb[j];
#pragma unroll
            for (int k = 0; k < DIN; ++k) a = fmaf(sh[wid][k], sW[k * DOUT + j], a);
            o[c] = a;
        }
        float4 r;
        r.x = fmaxf(acc.x * iv + o[0], 0.f);
        r.y = fmaxf(acc.y * iv + o[1], 0.f);
        r.z = fmaxf(acc.z * iv + o[2], 0.f);
        r.w = fmaxf(acc.w * iv + o[3], 0.f);
        ((float4*)out)[(size_t)v * Q + q] = r;
    }
}

// ---------------- head: out = h3 @ Wc + bc (16 -> 1) ----------------
__global__ void final_k(const float* __restrict__ h, const float* __restrict__ Wc,
                        const float* __restrict__ bc, float* __restrict__ out, int N) {
    int v = blockIdx.x * blockDim.x + threadIdx.x;
    if (v >= N) return;
    float acc = bc[0];
    const float4* hv = (const float4*)(h + (size_t)v * 16);
    const float4* w = (const float4*)Wc;
#pragma unroll
    for (int q = 0; q < 4; ++q) {
        float4 a = hv[q];
        float4 b4 = w[q];
        acc += a.x * b4.x + a.y * b4.y + a.z * b4.z + a.w * b4.w;
    }
    out[v] = acc;
}

extern "C" void kernel_launch(void* const* d_in, const int* in_sizes, int n_in,
                              void* d_out, int out_size, void* d_ws, size_t ws_size,
                              hipStream_t stream) {
    const float* x   = (const float*)d_in[0];
    const int*   ei  = (const int*)d_in[1];
    const float* Wl0 = (const float*)d_in[2];
    const float* Wr0 = (const float*)d_in[3];
    const float* b0  = (const float*)d_in[4];
    const float* Wl1 = (const float*)d_in[5];
    const float* Wr1 = (const float*)d_in[6];
    const float* b1  = (const float*)d_in[7];
    const float* Wl2 = (const float*)d_in[8];
    const float* Wr2 = (const float*)d_in[9];
    const float* b2  = (const float*)d_in[10];
    const float* Wc  = (const float*)d_in[11];
    const float* bc  = (const float*)d_in[12];
    float* out = (float*)d_out;

    const int N = NN;
    const int E = in_sizes[1] / 2;
    const int* src = ei;
    const int* dst = ei + E;
    const int M = NBK * HB;            // 200064 scan entries

    char* ws = (char*)d_ws;
    const size_t KB = 1 << 10;
    const size_t MB = 1 << 20;
    int*      gh   = (int*)(ws + 0);             // (M+1) ints ~ 0.8 MB
    int*      off  = (int*)(ws + 1 * MB);        // 400 KB
    float*    inv  = (float*)(ws + 1536 * KB);   // 400 KB
    int*      segs = (int*)(ws + 1950 * KB);     // 32 KB segment sums
    unsigned* pair = (unsigned*)(ws + 2 * MB);   // 12.8 MB packed edges
    int*      adj  = (int*)(ws + 15 * MB);       // 12.8 MB CSR adjacency
    char*     G    = ws + 28 * MB;               // 26 MB region
    char*     A    = ws + 54 * MB;               // 26 MB region (ends 80 MB)

    float* g0 = (float*)G;                       // 25.6 MB
    float* h1 = (float*)A;                       // 25.6 MB
    float* g1 = (float*)G;                       // 12.8 MB (g0 dead)
    float* h2 = (float*)(G + 13 * MB);           // 12.8 MB
    float* g2 = (float*)A;                       // 6.4 MB (h1 dead)
    float* h3 = (float*)(A + 7 * MB);            // 6.4 MB

    // ---- counting-sort CSR build (no global atomics anywhere) ----
    hist_k<<<HB, 256, 0, stream>>>(dst, E, gh);
    scanA_k<<<SCB, 256, 0, stream>>>(gh, M, segs);
    scanB_k<<<1, 1024, 0, stream>>>(segs, gh, M, E);
    scanC_k<<<SCB, 256, 0, stream>>>(gh, M, segs);
    scatter_pack_k<<<HB, 256, 0, stream>>>(src, dst, E, gh, pair);
    sort_bucket_k<<<NBK, 256, 0, stream>>>(pair, gh, adj, off, inv, N, E);

    // ---- layer 0: 64 -> 64 ----
    transform_k<64, 64><<<(N * 64 + 255) / 256, 256, 0, stream>>>(x, Wl0, g0, N);
    agg_combine_k<64, 64, 4><<<(N + 3) / 4, 256, 0, stream>>>(g0, off, adj, inv, x, Wr0, b0, h1, N);

    // ---- layer 1: 64 -> 32 ----
    transform_k<64, 32><<<(N * 32 + 255) / 256, 256, 0, stream>>>(h1, Wl1, g1, N);
    agg_combine_k<64, 32, 4><<<(N + 3) / 4, 256, 0, stream>>>(g1, off, adj, inv, h1, Wr1, b1, h2, N);

    // ---- layer 2: 32 -> 16 ----
    transform_k<32, 16><<<(N * 16 + 255) / 256, 256, 0, stream>>>(h2, Wl2, g2, N);
    agg_combine_k<32, 16, 4><<<(N + 3) / 4, 256, 0, stream>>>(g2, off, adj, inv, h2, Wr2, b2, h3, N);

    // ---- head: 16 -> 1 ----
    final_k<<<(N + 255) / 256, 256, 0, stream>>>(h3, Wc, bc, out, N);
}

// Round 8
// 442.165 us; speedup vs baseline: 7.1102x; 1.5096x over previous
//
#include <hip/hip_runtime.h>

// GraphSAGE: 3x SAGEConv(mean) + linear head.
// N=100000 nodes, E=3200000 edges, dims 64 -> 64 -> 32 -> 16 -> 1.
// Round 8 = round 7 with:
//  - g stored as bf16 (RNE), fp32 accumulate: halves gather bytes AND lines,
//    doubles effective L2 capacity (agg was 2.5TB/s L3-line-bound, FETCH 366MB).
//  - h@Wr moved out of agg's 16/64-lane epilogue into transform2_k
//    (computes g=h@Wl bf16 and r=h@Wr+b fp32 in one pass, node-paired).
//  - agg epilogue on all 64 lanes via LDS redistribute; writes h_next IN PLACE
//    over r (same elem, read-before-write per thread). Head fused into agg2.
//  - build pipeline (counting-sort CSR, block-exclusive writes) unchanged.
// agg-linearity: mean(h[src]) @ Wl == mean((h@Wl)[src]) -> transform first.

#define NN 100000
#define BSH 6                       // bucket = dst >> 6 (64 nodes)
#define NBK ((NN + 63) >> 6)        // 1563 buckets
#define HB 128                      // partition blocks
#define SRCMASK 0x1FFFF             // 17 bits, N=100000 < 2^17
#define NSEG 8192                   // scan segments
#define SCB 32                      // scan blocks (NSEG/256)

__device__ __forceinline__ unsigned f2bf(float f) {   // RNE fp32->bf16
    unsigned u = __float_as_uint(f);
    u += 0x7fffu + ((u >> 16) & 1u);
    return u >> 16;
}
__device__ __forceinline__ float bflo(unsigned u) { return __uint_as_float(u << 16); }
__device__ __forceinline__ float bfhi(unsigned u) { return __uint_as_float(u & 0xffff0000u); }

// ---- per-block histogram of dst buckets (LDS, no global atomics) ----
__global__ void hist_k(const int* __restrict__ dst, int E, int* __restrict__ gh) {
    __shared__ int lh[NBK];
    for (int i = threadIdx.x; i < NBK; i += blockDim.x) lh[i] = 0;
    __syncthreads();
    int c = blockIdx.x;
    int chunk = (E + HB - 1) / HB;
    int b0 = c * chunk, e0 = min(b0 + chunk, E);
    for (int e = b0 + threadIdx.x; e < e0; e += blockDim.x)
        atomicAdd(&lh[dst[e] >> BSH], 1);
    __syncthreads();
    for (int i = threadIdx.x; i < NBK; i += blockDim.x) gh[i * HB + c] = lh[i];
}

// ---- 3-phase parallel exclusive scan over gh[0..M) ----
__global__ void scanA_k(const int* __restrict__ gh, int M, int* __restrict__ segsum) {
    int t = blockIdx.x * blockDim.x + threadIdx.x;
    int cht = (M + NSEG - 1) / NSEG;
    int b0 = t * cht, e0 = min(b0 + cht, M);
    int s = 0;
    for (int i = b0; i < e0; ++i) s += gh[i];
    segsum[t] = s;
}

__global__ void scanB_k(int* __restrict__ segsum, int* __restrict__ gh, int M, int E) {
    __shared__ int part[1024];
    int tid = threadIdx.x;
    constexpr int SPT = NSEG / 1024;
    int loc[SPT];
    int s = 0;
#pragma unroll
    for (int k = 0; k < SPT; ++k) { loc[k] = segsum[tid * SPT + k]; s += loc[k]; }
    part[tid] = s;
    __syncthreads();
    for (int d = 1; d < 1024; d <<= 1) {
        int t = (tid >= d) ? part[tid - d] : 0;
        __syncthreads();
        part[tid] += t;
        __syncthreads();
    }
    int run = (tid == 0) ? 0 : part[tid - 1];
#pragma unroll
    for (int k = 0; k < SPT; ++k) { int t = loc[k]; segsum[tid * SPT + k] = run; run += t; }
    if (tid == 0) gh[M] = E;
}

__global__ void scanC_k(int* __restrict__ gh, int M, const int* __restrict__ segsum) {
    int t = blockIdx.x * blockDim.x + threadIdx.x;
    int cht = (M + NSEG - 1) / NSEG;
    int b0 = t * cht, e0 = min(b0 + cht, M);
    int run = segsum[t];
    for (int i = b0; i < e0; ++i) {
        int v = gh[i];
        gh[i] = run;
        run += v;
    }
}

// ---- place edges bucket-grouped; cursors block-private in LDS ----
__global__ void scatter_pack_k(const int* __restrict__ src, const int* __restrict__ dst,
                               int E, const int* __restrict__ gh,
                               unsigned* __restrict__ pair) {
    __shared__ int cur[NBK];
    int c = blockIdx.x;
    for (int i = threadIdx.x; i < NBK; i += blockDim.x) cur[i] = gh[i * HB + c];
    __syncthreads();
    int chunk = (E + HB - 1) / HB;
    int b0 = c * chunk, e0 = min(b0 + chunk, E);
    for (int e = b0 + threadIdx.x; e < e0; e += blockDim.x) {
        int dv = dst[e], sv = src[e];
        int p = atomicAdd(&cur[dv >> BSH], 1);
        pair[p] = (unsigned)sv | ((unsigned)(dv & 63) << 17);
    }
}

// ---- per-bucket counting sort -> per-node CSR (adj, off, inv) ----
__global__ void sort_bucket_k(const unsigned* __restrict__ pair, const int* __restrict__ gh,
                              int* __restrict__ adj, int* __restrict__ off,
                              float* __restrict__ inv, int N, int E) {
    __shared__ int lcnt[64];
    __shared__ int lbase[64];
    int b = blockIdx.x, tid = threadIdx.x;
    int base = gh[b * HB], endp = gh[(b + 1) * HB];
    int v0 = b << BSH;
    int nv = min(64, N - v0);
    if (tid < 64) lcnt[tid] = 0;
    __syncthreads();
    for (int i = base + tid; i < endp; i += blockDim.x)
        atomicAdd(&lcnt[pair[i] >> 17], 1);
    __syncthreads();
    if (tid == 0) {
        int run = 0;
        for (int d = 0; d < 64; ++d) { lbase[d] = run; run += lcnt[d]; }
    }
    __syncthreads();
    if (tid < nv) {
        off[v0 + tid] = base + lbase[tid];
        inv[v0 + tid] = 1.0f / (float)max(lcnt[tid], 1);
    }
    if (b == NBK - 1 && tid == 0) off[N] = E;
    if (tid < 64) lcnt[tid] = lbase[tid];
    __syncthreads();
    for (int i = base + tid; i < endp; i += blockDim.x) {
        unsigned u = pair[i];
        int dl = u >> 17;
        int p = base + atomicAdd(&lcnt[dl], 1);
        adj[p] = u & SRCMASK;
    }
}

// ---- transform2: g = h@Wl (bf16 packed), r = h@Wr + b (fp32) ----
// node-paired (2 nodes, 2 channels per thread) so LDS-read:FMA <= 2B/FMA.
template <int DIN, int DOUT>
__global__ void transform2_k(const float* __restrict__ h,
                             const float* __restrict__ Wl, const float* __restrict__ Wr,
                             const float* __restrict__ bias,
                             unsigned* __restrict__ g, float2* __restrict__ r, int N) {
    constexpr int JP = DOUT / 2;
    __shared__ float2 sWl[DIN * JP];
    __shared__ float2 sWr[DIN * JP];
    __shared__ float2 sb[JP];
    const float2* Wl2 = (const float2*)Wl;
    const float2* Wr2 = (const float2*)Wr;
    for (int i = threadIdx.x; i < DIN * JP; i += blockDim.x) { sWl[i] = Wl2[i]; sWr[i] = Wr2[i]; }
    if (threadIdx.x < JP) sb[threadIdx.x] = ((const float2*)bias)[threadIdx.x];
    __syncthreads();
    int idx = blockIdx.x * blockDim.x + threadIdx.x;
    int NP = N / 2;                    // N even
    if (idx >= NP * JP) return;
    int p = idx / JP, jp = idx % JP;
    int v0 = 2 * p, v1 = v0 + 1;
    const float* h0 = h + (size_t)v0 * DIN;
    const float* h1 = h + (size_t)v1 * DIN;
    float gl0x = 0, gl0y = 0, gl1x = 0, gl1y = 0;
    float gr0x = 0, gr0y = 0, gr1x = 0, gr1y = 0;
#pragma unroll
    for (int k = 0; k < DIN; ++k) {
        float2 wl = sWl[k * JP + jp];
        float2 wr = sWr[k * JP + jp];
        float a0 = h0[k], a1 = h1[k];
        gl0x = fmaf(a0, wl.x, gl0x); gl0y = fmaf(a0, wl.y, gl0y);
        gl1x = fmaf(a1, wl.x, gl1x); gl1y = fmaf(a1, wl.y, gl1y);
        gr0x = fmaf(a0, wr.x, gr0x); gr0y = fmaf(a0, wr.y, gr0y);
        gr1x = fmaf(a1, wr.x, gr1x); gr1y = fmaf(a1, wr.y, gr1y);
    }
    float2 bb = sb[jp];
    g[(size_t)v0 * JP + jp] = f2bf(gl0x) | (f2bf(gl0y) << 16);
    g[(size_t)v1 * JP + jp] = f2bf(gl1x) | (f2bf(gl1y) << 16);
    r[(size_t)v0 * JP + jp] = make_float2(gr0x + bb.x, gr0y + bb.y);
    r[(size_t)v1 * JP + jp] = make_float2(gr1x + bb.x, gr1y + bb.y);
}

// ---- agg: out = relu( mean-gather(g_bf16) + r ); optional fused head ----
// One wave per dst node (PULL). Q8 = DOUT/8 lanes x uint4 (8 bf16) per row;
// EPT = 64/Q8 edge groups, 4x unroll. NOTE: out may alias r (in-place).
template <int DOUT, int WAVES, int HEAD>
__global__ void agg_k(const unsigned* __restrict__ g, const int* __restrict__ off,
                      const int* __restrict__ adj, const float* __restrict__ invc,
                      const float* r, const float* __restrict__ Wc,
                      const float* __restrict__ bc, float* out, int N) {
    constexpr int Q8 = DOUT / 8;
    constexpr int EPT = 64 / Q8;
    __shared__ float sagg[WAVES][DOUT];
    int wid = threadIdx.x >> 6, lane = threadIdx.x & 63;
    int v = blockIdx.x * WAVES + wid;
    bool active = v < N;
    int q = lane & (Q8 - 1);
    int eg = lane / Q8;
    float acc[8] = {0, 0, 0, 0, 0, 0, 0, 0};
#define ACCU(U) do { \
        acc[0] += bflo(U.x); acc[1] += bfhi(U.x); \
        acc[2] += bflo(U.y); acc[3] += bfhi(U.y); \
        acc[4] += bflo(U.z); acc[5] += bfhi(U.z); \
        acc[6] += bflo(U.w); acc[7] += bfhi(U.w); } while (0)
    if (active) {
        int beg = off[v], end = off[v + 1];
        const uint4* g4 = (const uint4*)g;   // row = Q8 uint4s
        int i = beg + eg;
        for (; i + 3 * EPT < end; i += 4 * EPT) {
            int s0 = adj[i], s1 = adj[i + EPT], s2 = adj[i + 2 * EPT], s3 = adj[i + 3 * EPT];
            uint4 u0 = g4[(size_t)s0 * Q8 + q];
            uint4 u1 = g4[(size_t)s1 * Q8 + q];
            uint4 u2 = g4[(size_t)s2 * Q8 + q];
            uint4 u3 = g4[(size_t)s3 * Q8 + q];
            ACCU(u0); ACCU(u1); ACCU(u2); ACCU(u3);
        }
        for (; i < end; i += EPT) {
            int sv = adj[i];
            uint4 u = g4[(size_t)sv * Q8 + q];
            ACCU(u);
        }
#pragma unroll
        for (int d = Q8; d < 64; d <<= 1)
#pragma unroll
            for (int c = 0; c < 8; ++c) acc[c] += __shfl_xor(acc[c], d, 64);
        if (eg == 0) {
            float4* sp = (float4*)&sagg[wid][q * 8];
            sp[0] = make_float4(acc[0], acc[1], acc[2], acc[3]);
            sp[1] = make_float4(acc[4], acc[5], acc[6], acc[7]);
        }
    }
#undef ACCU
    __syncthreads();
    if (active && lane < DOUT) {
        float iv = invc[v];
        float val = fmaxf(fmaf(sagg[wid][lane], iv, r[(size_t)v * DOUT + lane]), 0.f);
        if (!HEAD) {
            out[(size_t)v * DOUT + lane] = val;   // may alias r: read-before-write per thread
        } else {
            float pp = val * Wc[lane];
#pragma unroll
            for (int d = 1; d < 16; d <<= 1) pp += __shfl_xor(pp, d, 64);
            if (lane == 0) out[v] = pp + bc[0];
        }
    }
}

extern "C" void kernel_launch(void* const* d_in, const int* in_sizes, int n_in,
                              void* d_out, int out_size, void* d_ws, size_t ws_size,
                              hipStream_t stream) {
    const float* x   = (const float*)d_in[0];
    const int*   ei  = (const int*)d_in[1];
    const float* Wl0 = (const float*)d_in[2];
    const float* Wr0 = (const float*)d_in[3];
    const float* b0  = (const float*)d_in[4];
    const float* Wl1 = (const float*)d_in[5];
    const float* Wr1 = (const float*)d_in[6];
    const float* b1  = (const float*)d_in[7];
    const float* Wl2 = (const float*)d_in[8];
    const float* Wr2 = (const float*)d_in[9];
    const float* b2  = (const float*)d_in[10];
    const float* Wc  = (const float*)d_in[11];
    const float* bc  = (const float*)d_in[12];
    float* out = (float*)d_out;

    const int N = NN;
    const int E = in_sizes[1] / 2;
    const int* src = ei;
    const int* dst = ei + E;
    const int M = NBK * HB;

    char* ws = (char*)d_ws;
    const size_t KB = 1 << 10;
    const size_t MB = 1 << 20;
    int*      gh   = (int*)(ws + 0);             // (M+1) ints ~0.8 MB
    int*      off  = (int*)(ws + 1 * MB);        // 400 KB
    float*    inv  = (float*)(ws + 1536 * KB);   // 400 KB
    int*      segs = (int*)(ws + 1950 * KB);     // 32 KB
    unsigned* pair = (unsigned*)(ws + 2 * MB);   // 12.2 MiB (dead after sort)
    int*      adj  = (int*)(ws + 15 * MB);       // 12.2 MiB CSR adjacency
    // layer buffers (sizes MiB): reuse regions by lifetime
    unsigned* g0 = (unsigned*)(ws + 54 * MB);    // bf16x2, 12.2
    float*    r0 = (float*)(ws + 28 * MB);       // fp32 25.6e6 B; h1 ALIASES r0
    float*    h1 = r0;
    unsigned* g1 = (unsigned*)(ws + 2 * MB);     // 6.1 (pair dead)
    float*    r1 = (float*)(ws + 54 * MB);       // 12.2 (g0 dead); h2 ALIASES r1
    float*    h2 = r1;
    unsigned* g2 = (unsigned*)(ws + 9 * MB);     // 3.1 (pair region)
    float*    r2 = (float*)(ws + 28 * MB);       // 6.1 (h1 dead after transform1)

    // ---- counting-sort CSR build (no global atomics anywhere) ----
    hist_k<<<HB, 256, 0, stream>>>(dst, E, gh);
    scanA_k<<<SCB, 256, 0, stream>>>(gh, M, segs);
    scanB_k<<<1, 1024, 0, stream>>>(segs, gh, M, E);
    scanC_k<<<SCB, 256, 0, stream>>>(gh, M, segs);
    scatter_pack_k<<<HB, 256, 0, stream>>>(src, dst, E, gh, pair);
    sort_bucket_k<<<NBK, 256, 0, stream>>>(pair, gh, adj, off, inv, N, E);

    // ---- layer 0: 64 -> 64 ----
    transform2_k<64, 64><<<(N / 2 * 32 + 255) / 256, 256, 0, stream>>>(x, Wl0, Wr0, b0, g0, (float2*)r0, N);
    agg_k<64, 4, 0><<<(N + 3) / 4, 256, 0, stream>>>(g0, off, adj, inv, r0, nullptr, nullptr, h1, N);

    // ---- layer 1: 64 -> 32 ----
    transform2_k<64, 32><<<(N / 2 * 16 + 255) / 256, 256, 0, stream>>>(h1, Wl1, Wr1, b1, g1, (float2*)r1, N);
    agg_k<32, 4, 0><<<(N + 3) / 4, 256, 0, stream>>>(g1, off, adj, inv, r1, nullptr, nullptr, h2, N);

    // ---- layer 2: 32 -> 16, head 16 -> 1 fused ----
    transform2_k<32, 16><<<(N / 2 * 8 + 255) / 256, 256, 0, stream>>>(h2, Wl2, Wr2, b2, g2, (float2*)r2, N);
    agg_k<16, 4, 1><<<(N + 3) / 4, 256, 0, stream>>>(g2, off, adj, inv, r2, Wc, bc, out, N);
}